// Round 14
// baseline (168.487 us; speedup 1.0000x reference)
//
#include <hip/hip_runtime.h>
#include <math.h>

#define NROWS 8192
#define KDIM  768            // bytes per row (i8)
#define BM 128
#define BN 128
#define NCH 12               // 64-byte k-chunks per row
#define GBYTES 12288         // bytes per 16-row group (12 chunks x 1KB)
#define KTILES 6             // kt = pair of chunks (128 B)
#define NBC 4                // bc tiles swept per block
#define NBCG (NROWS / BN / NBC)  // 16 -> grid 64*16 = 1024 = 4/CU

typedef int i32x4 __attribute__((ext_vector_type(4)));  // i8 MFMA A/B frag (16 B) and C/D

// monotonic float<->uint encoding so atomicMax(uint) == float max
static __device__ __forceinline__ unsigned enc_f(float f) {
    unsigned x = __float_as_uint(f);
    return (x & 0x80000000u) ? ~x : (x | 0x80000000u);
}
static __device__ __forceinline__ float dec_f(unsigned u) {
    unsigned x = (u & 0x80000000u) ? (u ^ 0x80000000u) : ~u;
    return __uint_as_float(x);
}

// Tiled quantized layout (R11-proven): for row-group g (16 rows), k-chunk c
// (64 B), a 1KB block at (g*12+c)*1024; byte l*16+j = row g*16+(l&15),
// k = c*64 + (l>>4)*16 + j == lane l's mfma_i32_16x16x64_i8 fragment.
__global__ __launch_bounds__(256) void normalize_quant_k(
        const float* __restrict__ ex, const float* __restrict__ ey,
        signed char* __restrict__ qt, float* __restrict__ scales,
        unsigned* __restrict__ out) {
    const int b = blockIdx.x;                 // 0..1023 = row group over [ex;ey]
    if (b < NROWS / 256)
        out[b * 256 + threadIdx.x] = enc_f(-INFINITY);
    const int wave = threadIdx.x >> 6, lane = threadIdx.x & 63;
    const int r_local = wave * 4 + (lane >> 4);     // 0..15 row within group
    const int l16 = lane & 15;
    const int grow = b * 16 + r_local;              // 0..16383 concatenated row
    const float* src = (b < 512) ? ex : ey;
    const int Rl = ((b & 511) * 16 + r_local);      // row within source
    const float4* xr = (const float4*)(src + (size_t)Rl * KDIM);

    float4 v[NCH];
    #pragma unroll
    for (int rep = 0; rep < NCH; ++rep) v[rep] = xr[l16 + 16 * rep];

    float ss = 0.f, am = 0.f;
    #pragma unroll
    for (int rep = 0; rep < NCH; ++rep) {
        ss += v[rep].x * v[rep].x + v[rep].y * v[rep].y +
              v[rep].z * v[rep].z + v[rep].w * v[rep].w;
        am = fmaxf(am, fmaxf(fmaxf(fabsf(v[rep].x), fabsf(v[rep].y)),
                             fmaxf(fabsf(v[rep].z), fabsf(v[rep].w))));
    }
    #pragma unroll
    for (int off = 1; off < 16; off <<= 1) {        // reduce within 16-lane group
        ss += __shfl_xor(ss, off);
        am = fmaxf(am, __shfl_xor(am, off));
    }
    const float scale = 1.0f / fmaxf(sqrtf(ss), 1e-8f);
    am = fmaxf(am * scale, 1e-12f);                 // amax of normalized row
    if (l16 == 0) scales[grow] = am * (1.0f / 127.0f);
    const float si = scale * (127.0f / am);         // raw -> int8 code

    signed char* gbase = qt + (size_t)b * GBYTES
                       + (l16 >> 2) * 256 + r_local * 16 + (l16 & 3) * 4;
    #pragma unroll
    for (int rep = 0; rep < NCH; ++rep) {
        int qx = min(127, max(-127, __float2int_rn(v[rep].x * si)));
        int qy = min(127, max(-127, __float2int_rn(v[rep].y * si)));
        int qz = min(127, max(-127, __float2int_rn(v[rep].z * si)));
        int qw = min(127, max(-127, __float2int_rn(v[rep].w * si)));
        *(int*)(gbase + rep * 1024) =
            (qx & 0xff) | ((qy & 0xff) << 8) | ((qz & 0xff) << 16) | ((qw & 0xff) << 24);
    }
}

// Hybrid GEMM: A fragments via shared LDS staging (16 KB/kt, half of R13's
// volume -> half the barrier drain), B fragments DIRECT from L2-resident
// tiled global (no barrier dependence). Splits the 1.57 GB of fragment reads
// across the LDS pipe and the vector-memory pipe instead of one of them.
// Region swizzle (R12-proven, FETCH 18.6 MB) keeps both operands per-XCD-L2.
__global__ __launch_bounds__(256, 4) void gemm_rowmax_i8_k(
        const signed char* __restrict__ A, const signed char* __restrict__ B,
        const float* __restrict__ sa, const float* __restrict__ sb,
        unsigned* __restrict__ out) {
    __shared__ signed char As[16 * 1024];  // [8 groups][2 chunk-parity][1KB]

    const int tid  = threadIdx.x;
    const int wave = tid >> 6, lane = tid & 63;

    // region swizzle (R12): region = 16 br x 8 bcg, id%8 picks region
    const int id    = blockIdx.x;
    const int reg8  = id & 7;
    const int inner = id >> 3;                        // 0..127 within region
    const int br  = (reg8 & 3) * 16 + (inner & 15);   // 0..63
    const int bcg = (reg8 >> 2) * 8 + (inner >> 4);   // 0..15

    const size_t laneoff = (size_t)lane * 16;
    // A staging: this wave stages chunks idx = wave*4+i (i<4): group g=idx>>1,
    // parity p=idx&1; source = A band block (g*12 + 2*kt + p), dst = (g*2+p)KB.
    const signed char* aG = A + (size_t)(br * 8) * GBYTES + laneoff;
    const int sg = (wave * 4) >> 1;                   // base group = wave*2
    signed char* lA = As + (wave * 4) * 1024;         // 4 KB per wave

    // compute geometry: wave 64x64 (2x2), 4x4 tiles of 16x16x64
    const int wgA = (wave >> 1) * 4;       // A group offset (local 0 or 4)
    const int wgB = (wave & 1) * 4;        // B group offset
    const int quad = lane >> 4, mrow = lane & 15;
    const int row0 = br * BM + wgA * 16 + quad * 4;
    const signed char* aFrag = As + (size_t)wgA * 2048 + laneoff;  // + (mi*2+ks)KB

    #pragma unroll 1
    for (int bi = 0; bi < NBC; ++bi) {
        const int bc = bcg * NBC + bi;
        const signed char* bT = B + (size_t)(bc * 8 + wgB) * GBYTES + laneoff;

        i32x4 acc[4][4] = {};

        #pragma unroll 1
        for (int kt = 0; kt < KTILES; ++kt) {
            __syncthreads();   // previous kt's A reads done before overwrite
            #pragma unroll
            for (int i = 0; i < 4; ++i) {
                const int g = sg + (i >> 1), p = i & 1;
                __builtin_amdgcn_global_load_lds(
                    (const __attribute__((address_space(1))) void*)
                        (aG + ((size_t)g * NCH + 2 * kt + p) * 1024),
                    (__attribute__((address_space(3))) void*)(lA + i * 1024),
                    16, 0, 0);
            }
            __syncthreads();   // A staging complete

            #pragma unroll 1
            for (int ks = 0; ks < 2; ++ks) {
                const int c = 2 * kt + ks;
                i32x4 af[4], bfr[4];
                #pragma unroll
                for (int ni = 0; ni < 4; ++ni)      // B: direct from tiled global
                    bfr[ni] = *(const i32x4*)(bT + (size_t)ni * GBYTES + c * 1024);
                #pragma unroll
                for (int mi = 0; mi < 4; ++mi)      // A: from LDS
                    af[mi] = *(const i32x4*)(aFrag + (mi * 2 + ks) * 1024);
                #pragma unroll
                for (int mi = 0; mi < 4; ++mi)
                    #pragma unroll
                    for (int ni = 0; ni < 4; ++ni)
                        acc[mi][ni] = __builtin_amdgcn_mfma_i32_16x16x64_i8(
                            af[mi], bfr[ni], acc[mi][ni], 0, 0, 0);
            }
        }

        // epilogue: fold sb[col] per ni, in-lane ni max, shfl-max over 16 cols,
        // then *sa[row]. C/D layout: col = lane&15, row = quad*4 + reg.
        float sbv[4];
        #pragma unroll
        for (int ni = 0; ni < 4; ++ni)
            sbv[ni] = sb[bc * BN + wgB * 16 + ni * 16 + mrow];
        #pragma unroll
        for (int mi = 0; mi < 4; ++mi) {
            #pragma unroll
            for (int r = 0; r < 4; ++r) {
                float v = fmaxf(fmaxf((float)acc[mi][0][r] * sbv[0],
                                      (float)acc[mi][1][r] * sbv[1]),
                                fmaxf((float)acc[mi][2][r] * sbv[2],
                                      (float)acc[mi][3][r] * sbv[3]));
                v = fmaxf(v, __shfl_xor(v, 1));
                v = fmaxf(v, __shfl_xor(v, 2));
                v = fmaxf(v, __shfl_xor(v, 4));
                v = fmaxf(v, __shfl_xor(v, 8));
                if (mrow == 0) {
                    const int row = row0 + mi * 16 + r;
                    atomicMax(&out[row], enc_f(v * sa[row]));
                }
            }
        }
    }
}

__global__ void decode_out_k(unsigned* __restrict__ u) {
    int i = blockIdx.x * 256 + threadIdx.x;
    ((float*)u)[i] = dec_f(u[i]);
}

extern "C" void kernel_launch(void* const* d_in, const int* in_sizes, int n_in,
                              void* d_out, int out_size, void* d_ws, size_t ws_size,
                              hipStream_t stream) {
    (void)in_sizes; (void)n_in; (void)out_size; (void)ws_size;
    const float* ex = (const float*)d_in[0];
    const float* ey = (const float*)d_in[1];
    // ws: qxT[512 groups * 12KB] ++ qyT[same] ++ scales[16384 f32]  (~12.65 MB)
    signed char* q = (signed char*)d_ws;
    float* scales  = (float*)(q + 2 * (size_t)512 * GBYTES);
    unsigned* outu = (unsigned*)d_out;

    normalize_quant_k<<<1024, 256, 0, stream>>>(ex, ey, q, scales, outu);
    gemm_rowmax_i8_k<<<(NROWS / BM) * NBCG, 256, 0, stream>>>(
        q, q + (size_t)512 * GBYTES, scales, scales + NROWS, outu);
    decode_out_k<<<NROWS / 256, 256, 0, stream>>>(outu);
}